// Round 11
// baseline (111.284 us; speedup 1.0000x reference)
//
#include <hip/hip_runtime.h>
#include <hip/hip_bf16.h>
#include <cstdint>

#define IN_F 256
#define OUT_F 64
#define NB 4
#define NN 4096
#define ALPHA 0.2f
#define LOG2E 1.4426950408889634f

typedef __attribute__((ext_vector_type(4))) float f32x4;
typedef __attribute__((ext_vector_type(4))) int i32x4;
typedef __attribute__((ext_vector_type(8))) short bf16x8;
typedef __attribute__((ext_vector_type(2))) unsigned long long u64x2;

static __device__ __forceinline__ ushort f2bf(float x) {
  uint32_t u = __float_as_uint(x);
  uint32_t r = (u + 0x7fffu + ((u >> 16) & 1u)) >> 16;
  return (ushort)r;
}

// async global -> LDS, 16B per lane
static __device__ __forceinline__ void gl16(const void* g, void* l) {
  __builtin_amdgcn_global_load_lds(
      (const __attribute__((address_space(1))) void*)g,
      (__attribute__((address_space(3))) void*)l, 16, 0, 0);
}
#define FENCE() asm volatile("" ::: "memory")

// ---------------- Kernel 01 (merged): blocks 0..511 = gemm, 512..1535 = adj bit-pack.
// gemm: Wh = h@W + bias; Wh1/Wh2 = (Wh.a1/a2)*LOG2E; WhT bf16 [B][64][N].
// pack: adj (int32 0/1) -> u64 mask[b][G 0..15][n][word 0..3], bit l of word j =
//       adj[b][n][G*256 + 4*l + j]  (4-way interleaved order from i32x4+ballot).
//       Reads: FULL 16KB rows, 16B/lane i32x4 (m13 pattern, ~6.3 TB/s capable).
//       Writes: LDS-transposed, 512B-coalesced segments.
__global__ __launch_bounds__(256) void k01_gemm_pack(
    const float* __restrict__ h, const float* __restrict__ W,
    const float* __restrict__ a, const float* __restrict__ bias,
    const int* __restrict__ adj,
    ushort* __restrict__ WhT, float* __restrict__ Wh1, float* __restrict__ Wh2,
    unsigned long long* __restrict__ maskp)
{
  __shared__ float hs[32][33];
  __shared__ float Ws[32][64];
  __shared__ unsigned long long mlds[16][66];   // [row][G*4+word], padded
  const int t = threadIdx.x;

  if (blockIdx.x < 512) {
    // ---------------- gemm part ----------------
    const int tx = t & 15;
    const int ty = t >> 4;
    const int row0 = blockIdx.x * 32;

    float acc[2][4] = {};

    for (int k0 = 0; k0 < IN_F; k0 += 32) {
      {
        int r = t >> 3, c4 = t & 7;
        *(f32x4*)&hs[r][c4 * 4] =
            *(const f32x4*)(h + (size_t)(row0 + r) * IN_F + k0 + c4 * 4);
      }
      #pragma unroll
      for (int s = 0; s < 2; ++s) {
        int f4 = t + 256 * s;
        int kk = f4 >> 4, c4 = f4 & 15;
        *(f32x4*)&Ws[kk][c4 * 4] = *(const f32x4*)(W + (size_t)(k0 + kk) * OUT_F + c4 * 4);
      }
      __syncthreads();
      #pragma unroll 8
      for (int kk = 0; kk < 32; ++kk) {
        f32x4 bv = *(const f32x4*)&Ws[kk][tx * 4];
        float av0 = hs[ty * 2 + 0][kk];
        float av1 = hs[ty * 2 + 1][kk];
        #pragma unroll
        for (int j = 0; j < 4; ++j) {
          acc[0][j] += av0 * bv[j];
          acc[1][j] += av1 * bv[j];
        }
      }
      __syncthreads();
    }

    #pragma unroll
    for (int i = 0; i < 2; ++i) {
      int row = row0 + ty * 2 + i;
      float s1 = 0.f, s2 = 0.f;
      #pragma unroll
      for (int j = 0; j < 4; ++j) {
        float v = acc[i][j] + bias[tx * 4 + j];
        acc[i][j] = v;
        s1 += v * a[tx * 4 + j];
        s2 += v * a[64 + tx * 4 + j];
      }
      #pragma unroll
      for (int off = 1; off < 16; off <<= 1) {
        s1 += __shfl_xor(s1, off);
        s2 += __shfl_xor(s2, off);
      }
      if (tx == 0) { Wh1[row] = s1 * LOG2E; Wh2[row] = s2 * LOG2E; }
      int bb = row >> 12;
      int n  = row & 4095;
      #pragma unroll
      for (int j = 0; j < 4; ++j) {
        WhT[(((size_t)(bb * OUT_F + tx * 4 + j)) << 12) + n] = f2bf(acc[i][j]);
      }
    }
  } else {
    // ---------------- pack part ----------------
    const int pbid = blockIdx.x - 512;     // 0..1023
    const int b    = pbid >> 8;
    const int n0   = (pbid & 255) << 4;    // 16-row band
    const int l    = t & 63;
    const int w    = t >> 6;               // wave -> rows w*4..w*4+3

    #pragma unroll
    for (int rr = 0; rr < 4; ++rr) {
      const int rl = (w << 2) + rr;
      const int* rowp = adj + ((size_t)b << 24) + ((size_t)(n0 + rl) << 12) + (l << 2);
      #pragma unroll 8
      for (int j = 0; j < 16; ++j) {          // full 16KB row, contiguous
        i32x4 v = *(const i32x4*)(rowp + (j << 8));
        unsigned long long m0 = __ballot(v[0] != 0);
        unsigned long long m1 = __ballot(v[1] != 0);
        unsigned long long m2 = __ballot(v[2] != 0);
        unsigned long long m3 = __ballot(v[3] != 0);
        if (l == 0) {
          u64x2 lo; lo[0] = m0; lo[1] = m1;
          u64x2 hi; hi[0] = m2; hi[1] = m3;
          *(u64x2*)&mlds[rl][(j << 2)]     = lo;
          *(u64x2*)&mlds[rl][(j << 2) + 2] = hi;
        }
      }
    }
    __syncthreads();
    // coalesced write-out: [b][G][n][word], 512B runs per G
    #pragma unroll
    for (int i = 0; i < 4; ++i) {
      int e   = (i << 8) + t;                // 0..1023
      int G   = e >> 6;
      int rl  = (e >> 2) & 15;
      int ww  = e & 3;
      maskp[(((size_t)(b * 16 + G) << 12) + n0 + rl) * 4 + ww] = mlds[rl][G * 4 + ww];
    }
  }
}

// ---------------- Kernel 2: fused masked softmax + PV, bitmask-fed
// grid (64, 4), 512 threads = 8 waves = (4 row-quarters) x (2 K-halves).
// Block: 64 rows x 64 out cols, K-step 64 cols, 64 steps.
// Mask panel [G][row][word] (32KB) + Wh2 (16KB) staged once in prologue;
// WhT tile ring (8KB/step, depth 4, L2-resident) with counted vmcnt
// + raw s_barrier. Interleaved mask decode: per 4 steps read 4 u64 words;
// per step sel[w] = (mw[w]>>B0)&3, p[i] tests bit (i>>2) of sel[i&3].
// No softmax shift (cancels in P/sum; |e| small in this regime).
#define NDEPTH 4
#define WHT_BUF 8192
#define MASK_OFF 32768    /* 4*8192 */
#define WH2_OFF  65536    /* 32768 + 32768 */
#define LDS_TOTAL 81920   /* + 16384 */
__global__ __launch_bounds__(512, 1) void k2_attn(
    const unsigned long long* __restrict__ maskp, const ushort* __restrict__ WhT,
    const float* __restrict__ Wh1, const float* __restrict__ Wh2,
    float* __restrict__ out)
{
  extern __shared__ char smem[];
  const int t  = threadIdx.x;        // 0..511
  const int l  = t & 63;
  const int w  = t >> 6;             // 0..7
  const int rq = w >> 1;             // row quarter 0..3
  const int kq = w & 1;              // K half of the 64-col step
  const int g  = l >> 4;             // k-subgroup 0..3
  const int lr = l & 15;
  const int b  = blockIdx.y;
  const int r0 = blockIdx.x << 6;

  const int   rowl = rq * 16 + lr;
  const float wh1  = Wh1[(b << 12) + r0 + rowl];   // already * LOG2E
  asm volatile("" :: "v"(wh1));

  // ---- WhT staging: 1 gl16/thread/step (pre-inverse-swizzled source, rule 21)
  const ushort* whb = WhT + ((size_t)(b * OUT_F) << 12);
  const int fW = t >> 3, chW = (t & 7) ^ (fW & 7);
  const ushort* srcW = whb + ((size_t)fW << 12) + chW * 8;
  const int ldsW = t << 4;
  auto STAGE_W = [&](int s) {
    gl16(srcW + (s << 6), smem + (s & 3) * WHT_BUF + ldsW);
  };

  // ---- accumulators
  f32x4 a0 = {0.f,0.f,0.f,0.f}, a1 = {0.f,0.f,0.f,0.f};
  f32x4 a2 = {0.f,0.f,0.f,0.f}, a3 = {0.f,0.f,0.f,0.f};
  f32x4 as = {0.f,0.f,0.f,0.f};
  bf16x8 ones;
  #pragma unroll
  for (int i = 0; i < 8; ++i) ones[i] = (short)0x3F80;

  const int offW = (kq * 64 + g * 16) ^ ((lr & 7) << 4);

  unsigned long long mw0 = 0, mw1 = 0, mw2 = 0, mw3 = 0;

  auto COMPUTE = [&](int s) {
    const char* baseW = smem + (s & 3) * WHT_BUF;
    bf16x8 b0 = *(const bf16x8*)(baseW + (lr     ) * 128 + offW);
    bf16x8 b1 = *(const bf16x8*)(baseW + (lr + 16) * 128 + offW);
    bf16x8 b2 = *(const bf16x8*)(baseW + (lr + 32) * 128 + offW);
    bf16x8 b3 = *(const bf16x8*)(baseW + (lr + 48) * 128 + offW);
    const char* w2b = smem + WH2_OFF + (s << 8) + kq * 128 + g * 32;
    f32x4 w20 = *(const f32x4*)(w2b);
    f32x4 w21 = *(const f32x4*)(w2b + 16);

    // interleaved-mask decode: col s*64+kq*32+g*8+i -> word i&3, bit B0+(i>>2)
    const uint32_t B0 = ((s & 3) << 4) + (kq << 3) + (g << 1);
    uint32_t selv[4];
    selv[0] = (uint32_t)(mw0 >> B0) & 3u;
    selv[1] = (uint32_t)(mw1 >> B0) & 3u;
    selv[2] = (uint32_t)(mw2 >> B0) & 3u;
    selv[3] = (uint32_t)(mw3 >> B0) & 3u;

    float p[8];
    #pragma unroll
    for (int i = 0; i < 8; ++i) {
      float w2 = (i < 4) ? w20[i] : w21[i - 4];
      float s_ = wh1 + w2;                                      // LOG2E-scaled
      float lk = fmaf(ALPHA, fminf(s_, 0.f), fmaxf(s_, 0.f));   // LeakyReLU
      float pe = exp2f(lk);
      p[i] = (selv[i & 3] & (i < 4 ? 1u : 2u)) ? pe : 0.0f;
    }
    union { bf16x8 v; uint32_t u[4]; } af;
    #pragma unroll
    for (int i = 0; i < 4; ++i)
      asm("v_cvt_pk_bf16_f32 %0, %1, %2" : "=v"(af.u[i]) : "v"(p[2*i]), "v"(p[2*i+1]));

    as = __builtin_amdgcn_mfma_f32_16x16x32_bf16(af.v, ones, as, 0, 0, 0);
    a0 = __builtin_amdgcn_mfma_f32_16x16x32_bf16(af.v, b0,   a0, 0, 0, 0);
    a1 = __builtin_amdgcn_mfma_f32_16x16x32_bf16(af.v, b1,   a1, 0, 0, 0);
    a2 = __builtin_amdgcn_mfma_f32_16x16x32_bf16(af.v, b2,   a2, 0, 0, 0);
    a3 = __builtin_amdgcn_mfma_f32_16x16x32_bf16(af.v, b3,   a3, 0, 0, 0);
  };

  // ---- prologue: mask panel [G][row][word] (4 gl16), wh2 (2), WhT 0..2 (3)
  {
    const char* maskb = (const char*)maskp + ((size_t)b << 21);   // b * 2MB
    #pragma unroll
    for (int i = 0; i < 4; ++i) {
      int u   = (i << 9) + t;          // 0..2047 16B units
      int G   = u >> 7;
      int q   = u & 127;
      int row = q >> 1, hh = q & 1;
      const char* src = maskb + ((size_t)(G * 4096 + r0 + row)) * 32 + hh * 16;
      gl16(src, smem + MASK_OFF + (u << 4));
    }
  }
  {
    const float* w2src = Wh2 + (b << 12);
    gl16(w2src + (t << 2),         smem + WH2_OFF + (t << 4));
    gl16(w2src + ((t + 512) << 2), smem + WH2_OFF + 8192 + (t << 4));
  }
  FENCE();
  STAGE_W(0); STAGE_W(1); STAGE_W(2);
  FENCE();

  // ---- main loop: 64 steps, ring of 4, stage s+3 after compute, 1 barrier/step
  for (int s = 0; s < 64; ++s) {
    if (s < 62)      asm volatile("s_waitcnt vmcnt(2)" ::: "memory");
    else if (s == 62) asm volatile("s_waitcnt vmcnt(1)" ::: "memory");
    else              asm volatile("s_waitcnt vmcnt(0)" ::: "memory");
    __builtin_amdgcn_s_barrier();
    if ((s & 3) == 0) {   // refresh this row's 4 mask words for the next 4 steps
      const unsigned long long* mp = (const unsigned long long*)
          (smem + MASK_OFF + ((s >> 2) << 11) + rowl * 32);
      mw0 = mp[0]; mw1 = mp[1]; mw2 = mp[2]; mw3 = mp[3];
    }
    COMPUTE(s);
    FENCE();
    if (s < 61) STAGE_W(s + 3);
    FENCE();
  }

  // ---- epilogue: cross-kq combine via LDS overlay
  __syncthreads();
  float* sacc = (float*)smem;                  // [2][64][68]
  float* ssum = (float*)(smem + 34816);        // [2][64]
  #pragma unroll
  for (int r = 0; r < 4; ++r) {
    int rr = rq * 16 + g * 4 + r;              // C/D: row = 4*(l>>4)+r, col = l&15
    float* dst = sacc + (kq * 64 + rr) * 68;
    dst[ 0 + lr] = a0[r];
    dst[16 + lr] = a1[r];
    dst[32 + lr] = a2[r];
    dst[48 + lr] = a3[r];
    if (lr == 0) ssum[kq * 64 + rr] = as[r];
  }
  __syncthreads();

  const int row = t >> 3;               // 0..63
  const int c0  = (t & 7) << 3;         // 0..56
  const float* p0 = sacc + row * 68;
  const float* p1 = sacc + (64 + row) * 68;
  float d = ssum[row] + ssum[64 + row];
  float inv = 1.0f / d;
  f32x4 o0, o1;
  #pragma unroll
  for (int j = 0; j < 4; ++j) {
    float x = (p0[c0 + j] + p1[c0 + j]) * inv;
    o0[j] = x > 0.f ? x : expm1f(x);
    float y = (p0[c0 + 4 + j] + p1[c0 + 4 + j]) * inv;
    o1[j] = y > 0.f ? y : expm1f(y);
  }
  size_t ob = ((size_t)((b << 12) + r0 + row) << 6) + c0;
  *(f32x4*)(out + ob)     = o0;
  *(f32x4*)(out + ob + 4) = o1;
}

extern "C" void kernel_launch(void* const* d_in, const int* in_sizes, int n_in,
                              void* d_out, int out_size, void* d_ws, size_t ws_size,
                              hipStream_t stream) {
  const float* h    = (const float*)d_in[0];
  const int*   adj  = (const int*)d_in[1];
  const float* W    = (const float*)d_in[2];
  const float* a    = (const float*)d_in[3];
  const float* bias = (const float*)d_in[4];
  float* out = (float*)d_out;

  char* ws = (char*)d_ws;
  ushort* WhT = (ushort*)ws;                                   // 2 MB
  float*  Wh1 = (float*)(ws + (size_t)NB * OUT_F * NN * 2);    // 64 KB
  float*  Wh2 = Wh1 + NB * NN;                                 // 64 KB
  unsigned long long* maskp =
      (unsigned long long*)(ws + (size_t)NB * OUT_F * NN * 2 + 2 * NB * NN * 4);  // 8 MB

  (void)hipFuncSetAttribute((const void*)k2_attn,
                            hipFuncAttributeMaxDynamicSharedMemorySize, LDS_TOTAL);

  k01_gemm_pack<<<dim3(512 + 1024), 256, 0, stream>>>(h, W, a, bias, adj,
                                                      WhT, Wh1, Wh2, maskp);
  k2_attn<<<dim3(NN / 64, NB), 512, LDS_TOTAL, stream>>>(maskp, WhT, Wh1, Wh2, out);
}